// Round 5
// baseline (122.066 us; speedup 1.0000x reference)
//
#include <hip/hip_runtime.h>

// Problem constants: B=4, S=512, H=256
#define Bn 4
#define Sn 512
#define Hn 256

#define CC   2.8853900817779268f   // 2*log2(e)
#define L2E  1.4426950408889634f

typedef __attribute__((ext_vector_type(4))) float f32x4;
typedef __attribute__((ext_vector_type(8))) short short8;

__device__ __forceinline__ unsigned short bf16rn(float f) {
    unsigned int u = __float_as_uint(f);
    u += 0x7fffu + ((u >> 16) & 1u);
    return (unsigned short)(u >> 16);
}
__device__ __forceinline__ float bf16tof(unsigned short b) {
    return __uint_as_float(((unsigned int)b) << 16);
}

// ---------------------------------------------------------------------------
// gemm R16 (kept verbatim): 32-row m-tile, K in two halves of 128, LDS
// 60.9KB -> 2 blocks/CU. R15->R16 structural change moved total by 0.4us
// (noise) -> gemm is small (<~10us by op-count); not worth further rounds.
// ---------------------------------------------------------------------------
__global__ __launch_bounds__(512, 4) void gemm_kernel(
    const float* __restrict__ h,  const float* __restrict__ Wt,
    const float* __restrict__ Wp, const float* __restrict__ Wa,
    const float* __restrict__ ba, const float* __restrict__ bh,
    float* __restrict__ Egt, float* __restrict__ Egp4,
    float* __restrict__ wa2, float* __restrict__ cst)
{
    // A1@0 A2@8704 (32x136 shorts) B1@17408 B2@34816 (64x136 shorts)
    // tile@52224 (32x68 f32; reused as ct) red4@60928
    __shared__ char lds[60944];
    unsigned short* A1 = (unsigned short*)lds;
    unsigned short* A2 = (unsigned short*)(lds + 8704);
    unsigned short* B1 = (unsigned short*)(lds + 17408);
    unsigned short* B2 = (unsigned short*)(lds + 34816);
    float* tile = (float*)(lds + 52224);
    float* red4 = (float*)(lds + 60928);

    const int tid = threadIdx.x;            // 0..511
    const int mb  = blockIdx.x >> 3;        // 0..63 (32-row m-tiles)
    const int nb  = blockIdx.x & 7;
    const int m0  = mb * 32;
    const bool isT = (nb < 4);
    const int n0  = (isT ? nb : nb - 4) * 64;
    const float* __restrict__ W = isT ? Wt : Wp;

    if (blockIdx.x == 0) {
        if (tid < 256) {
            float wv = Wa[tid];
#pragma unroll
            for (int off = 32; off >= 1; off >>= 1) wv += __shfl_xor(wv, off, 64);
            if ((tid & 63) == 0) red4[tid >> 6] = wv;
        }
        __syncthreads();
        if (tid < 256) wa2[tid] = -2.0f * Wa[tid];
        if (tid == 0)
            cst[0] = -L2E * ((red4[0] + red4[1] + red4[2] + red4[3]) + ba[0]);
    }

    const int w    = tid >> 6;              // 0..7
    const int w2   = w & 3;                 // n-quadrant
    const int mh   = w >> 2;                // m-half
    const int lane = tid & 63;
    const int quad = lane >> 4;
    const int l15  = lane & 15;

    f32x4 acc = (f32x4){0.f, 0.f, 0.f, 0.f};

    for (int kh2 = 0; kh2 < 2; kh2++) {
        const int K0 = kh2 << 7;
        __syncthreads();

        {
            const int row = tid >> 4;
            const int seg = (tid & 15) * 8;
            const float* __restrict__ src = h + (m0 + row) * Hn + K0 + seg;
            unsigned int* d1 = (unsigned int*)A1 + row * 68 + (seg >> 1);
            unsigned int* d2 = (unsigned int*)A2 + row * 68 + (seg >> 1);
#pragma unroll
            for (int i = 0; i < 2; i++) {
                const float4 v = ((const float4*)src)[i];
                const float f[4] = {v.x, v.y, v.z, v.w};
                unsigned short b1[4], b2[4];
#pragma unroll
                for (int j = 0; j < 4; j++) {
                    b1[j] = bf16rn(f[j]);
                    b2[j] = bf16rn(f[j] - bf16tof(b1[j]));
                }
                d1[2 * i]     = (unsigned)b1[0] | ((unsigned)b1[1] << 16);
                d1[2 * i + 1] = (unsigned)b1[2] | ((unsigned)b1[3] << 16);
                d2[2 * i]     = (unsigned)b2[0] | ((unsigned)b2[1] << 16);
                d2[2 * i + 1] = (unsigned)b2[2] | ((unsigned)b2[3] << 16);
            }
        }

        for (int kt = 0; kt < 4; kt++) {
            const int koff = K0 + kt * 32;
            if (kt) __syncthreads();
            {
                const int kr = tid >> 4;
                const int nq = tid & 15;
                *(float4*)&tile[kr * 68 + nq * 4] =
                    *(const float4*)&W[(koff + kr) * Hn + n0 + nq * 4];
            }
            __syncthreads();
            {
                const int n  = tid >> 3;
                const int p0 = (tid & 7) * 2;
                const float f0 = tile[(2 * p0    ) * 68 + n];
                const float f1 = tile[(2 * p0 + 1) * 68 + n];
                const float f2 = tile[(2 * p0 + 2) * 68 + n];
                const float f3 = tile[(2 * p0 + 3) * 68 + n];
                const unsigned short a0 = bf16rn(f0), a1 = bf16rn(f1);
                const unsigned short a2 = bf16rn(f2), a3 = bf16rn(f3);
                const unsigned short c0 = bf16rn(f0 - bf16tof(a0));
                const unsigned short c1 = bf16rn(f1 - bf16tof(a1));
                const unsigned short c2 = bf16rn(f2 - bf16tof(a2));
                const unsigned short c3 = bf16rn(f3 - bf16tof(a3));
                unsigned int* o1 = (unsigned int*)B1 + n * 68 + kt * 16 + p0;
                unsigned int* o2 = (unsigned int*)B2 + n * 68 + kt * 16 + p0;
                o1[0] = (unsigned)a0 | ((unsigned)a1 << 16);
                o1[1] = (unsigned)a2 | ((unsigned)a3 << 16);
                o2[0] = (unsigned)c0 | ((unsigned)c1 << 16);
                o2[1] = (unsigned)c2 | ((unsigned)c3 << 16);
            }
        }
        __syncthreads();

#pragma unroll
        for (int ks = 0; ks < 128; ks += 32) {
            const int bof = (w2 * 16 + l15) * 136 + ks + quad * 8;
            const short8 b1 = *(const short8*)(B1 + bof);
            const short8 b2 = *(const short8*)(B2 + bof);
            const int aof = (mh * 16 + l15) * 136 + ks + quad * 8;
            const short8 a1 = *(const short8*)(A1 + aof);
            const short8 a2 = *(const short8*)(A2 + aof);
            acc = __builtin_amdgcn_mfma_f32_16x16x32_bf16(a1, b1, acc, 0, 0, 0);
            acc = __builtin_amdgcn_mfma_f32_16x16x32_bf16(a1, b2, acc, 0, 0, 0);
            acc = __builtin_amdgcn_mfma_f32_16x16x32_bf16(a2, b1, acc, 0, 0, 0);
        }
    }

    float* ct = tile;
#pragma unroll
    for (int r = 0; r < 4; r++)
        ct[(mh * 16 + quad * 4 + r) * 68 + w2 * 16 + l15] = acc[r];
    __syncthreads();

    const int b  = m0 >> 9;
    const int s0 = m0 & 511;
    if (isT) {
        const int n0g = nb * 64;
        const int mr = tid >> 4, nq = tid & 15;
        const float4 c  = *(const float4*)&ct[mr * 68 + nq * 4];
        const float4 bv = *(const float4*)&bh[n0g + nq * 4];
        float4 o;
        o.x = __builtin_amdgcn_exp2f((c.x + bv.x) * CC);
        o.y = __builtin_amdgcn_exp2f((c.y + bv.y) * CC);
        o.z = __builtin_amdgcn_exp2f((c.z + bv.z) * CC);
        o.w = __builtin_amdgcn_exp2f((c.w + bv.w) * CC);
        *(float4*)&Egt[(m0 + mr) * Hn + n0g + nq * 4] = o;
    } else {
        const int kq0 = (nb - 4) * 16;
        const int mr = tid & 31, nq = tid >> 5;
        const float4 c = *(const float4*)&ct[mr * 68 + nq * 4];
        float4 o;
        o.x = __builtin_amdgcn_exp2f(c.x * CC);
        o.y = __builtin_amdgcn_exp2f(c.y * CC);
        o.z = __builtin_amdgcn_exp2f(c.z * CC);
        o.w = __builtin_amdgcn_exp2f(c.w * CC);
        *(float4*)&Egp4[b * 131072 + (kq0 + nq) * 2048 + (s0 + mr) * 4] = o;
    }
}

// ---------------------------------------------------------------------------
// attn R20: shrink the sync domain. R13/R18 used 1024-thr blocks (16 waves,
// 6 barriers, 2 blocks/CU): when a block hits a barrier/drain, half the CU
// idles -> VALUBusy 61%, idle 39%. Same total work restructured as 512-thr
// blocks x 1024 blocks (2 t-rows/block, FULL k-range per thread):
//  - kh cross-half exchange (accl 8KB + 1 barrier) eliminated entirely
//  - part no longer aliases accl/red -> pre-alias barrier eliminated
//  - two-stage part reduction -> single stage (all 8 q write, one barrier)
//  - 6 barriers -> 3, each gathering 8 waves instead of 16
//  - LDS 40960 -> ~20.5KB -> 4 blocks/CU: 2x more independent blocks to
//    fill barrier/drain bubbles (still 2048 thr/CU).
// Per-k-term arithmetic identical; only fp32 k-summation order changes
// (single 64-group pass vs two 32-group halves) -> ~1e-5 vs 3.3e-3 threshold.
// ---------------------------------------------------------------------------
__global__ __launch_bounds__(512, 8) void attn_kernel(
    const float* __restrict__ hsrc, const float* __restrict__ Egt,
    const float* __restrict__ Egp4, const float* __restrict__ wa2,
    const float* __restrict__ cst,
    float* __restrict__ out, float* __restrict__ out_attn)
{
    __shared__ float  attn_l[2 * 512];     // 4 KB
    __shared__ float  red[16];             // 2 rows x 8 waves
    __shared__ float4 part[8 * 2 * 64];    // 16 KB: [q][r][c4]

    const int tid = threadIdx.x;           // 0..511
    const int b   = blockIdx.x & 3;
    const int t0  = (blockIdx.x >> 2) << 1;   // 2 t-rows per block

    const float* __restrict__ egt = Egt + (b * Sn + t0) * Hn;   // block-uniform
    const float4* __restrict__ ep = (const float4*)(Egp4 + b * (Hn * Sn));

    float acc[2] = {0.f, 0.f};

    // 1-deep prefetch of wave-uniform eg/w4 (s_load pipeline), as in R13
    float4 w4c  = *(const float4*)&wa2[0];
    float4 eg0c = *(const float4*)&egt[0 * Hn];
    float4 eg1c = *(const float4*)&egt[1 * Hn];

#pragma unroll 2
    for (int kk = 0; kk < 64; kk++) {
        const int k4n = (kk + 1) & 63;
        const float4 w4n  = *(const float4*)&wa2[k4n * 4];
        const float4 eg0n = *(const float4*)&egt[0 * Hn + k4n * 4];
        const float4 eg1n = *(const float4*)&egt[1 * Hn + k4n * 4];

        const float4 cur = ep[kk * Sn + tid];   // coalesced vector load

        const float4 egs[2] = {eg0c, eg1c};
#pragma unroll
        for (int r = 0; r < 2; r++) {
            const float4 eg = egs[r];
            const float d1 = fmaf(cur.x, eg.x, 1.0f);
            const float d2 = fmaf(cur.y, eg.y, 1.0f);
            const float d3 = fmaf(cur.z, eg.z, 1.0f);
            const float d4 = fmaf(cur.w, eg.w, 1.0f);
            const float p12 = d1 * d2, p34 = d3 * d4;
            const float n12 = fmaf(w4c.x, d2, w4c.y * d1);
            const float n34 = fmaf(w4c.z, d4, w4c.w * d3);
            const float num = fmaf(n12, p34, n34 * p12);
            acc[r] = fmaf(num, __builtin_amdgcn_rcpf(p12 * p34), acc[r]);
        }

        w4c = w4n; eg0c = eg0n; eg1c = eg1n;
    }

    // ---- softmax: every thread owns full k-range of its 2 rows ----
    float ex[2];
    const float k0 = cst[0];
#pragma unroll
    for (int i = 0; i < 2; i++) {
        const float a   = acc[i];
        const float e1  = __builtin_amdgcn_exp2f(fmaf(-L2E, a, k0));
        const float sig = __builtin_amdgcn_rcpf(1.0f + e1);
        ex[i] = __builtin_amdgcn_exp2f(L2E * sig);   // sig in (0,1)
    }
    const int lane = tid & 63, wid = tid >> 6;       // wid 0..7
#pragma unroll
    for (int i = 0; i < 2; i++) {
        float v = ex[i];
#pragma unroll
        for (int off = 32; off >= 1; off >>= 1) v += __shfl_xor(v, off, 64);
        if (lane == 0) red[i * 8 + wid] = v;
    }
    __syncthreads();

#pragma unroll
    for (int i = 0; i < 2; i++) {
        float tot = 0.f;
#pragma unroll
        for (int j = 0; j < 8; j++) tot += red[i * 8 + j];
        const float a = ex[i] * __builtin_amdgcn_rcpf(tot);
        attn_l[i * 512 + tid] = a;
        out_attn[(b * Sn + t0 + i) * Sn + tid] = a;
    }
    __syncthreads();

    // ---- phase 2: out rows = attn @ h. 8 q-groups of 64 t' each ----
    const int c4 = tid & 63;
    const int q  = tid >> 6;                 // 0..7, wave-uniform

    const float* __restrict__ hb = hsrc + (b * Sn + q * 64) * Hn + c4 * 4;

    float4 a4[2];
#pragma unroll
    for (int r = 0; r < 2; r++) a4[r] = (float4){0.f, 0.f, 0.f, 0.f};

#pragma unroll 2
    for (int j4 = 0; j4 < 16; j4++) {
        float4 wv[2];
#pragma unroll
        for (int r = 0; r < 2; r++)
            wv[r] = *(const float4*)&attn_l[r * 512 + q * 64 + j4 * 4];  // bcast
#pragma unroll
        for (int i = 0; i < 4; i++) {
            const float4 hv = *(const float4*)&hb[(j4 * 4 + i) * Hn];
#pragma unroll
            for (int r = 0; r < 2; r++) {
                const float wr = ((const float*)&wv[r])[i];
                a4[r].x = fmaf(wr, hv.x, a4[r].x);
                a4[r].y = fmaf(wr, hv.y, a4[r].y);
                a4[r].z = fmaf(wr, hv.z, a4[r].z);
                a4[r].w = fmaf(wr, hv.w, a4[r].w);
            }
        }
    }

    // part is dedicated memory (no aliasing) -> no barrier needed pre-write
#pragma unroll
    for (int r = 0; r < 2; r++) part[(q * 2 + r) * 64 + c4] = a4[r];
    __syncthreads();

    // final: 512 threads = 256 cols x 2 rows; sum the 8 q-partials
    {
        const int col = tid & 255;
        const int r   = tid >> 8;
        const float* pf = (const float*)part;
        float s = 0.f;
#pragma unroll
        for (int qq = 0; qq < 8; qq++)
            s += pf[((qq * 2 + r) * 64 + (col >> 2)) * 4 + (col & 3)];
        out[(b * Sn + t0 + r) * Hn + col] = s;
    }
}

extern "C" void kernel_launch(void* const* d_in, const int* in_sizes, int n_in,
                              void* d_out, int out_size, void* d_ws, size_t ws_size,
                              hipStream_t stream) {
    const float* h   = (const float*)d_in[0];
    const float* Wt  = (const float*)d_in[1];
    const float* Wtp = (const float*)d_in[2];
    const float* bh  = (const float*)d_in[3];
    const float* Wa  = (const float*)d_in[4];
    const float* ba  = (const float*)d_in[5];

    float* out      = (float*)d_out;                 // (B,S,H) = 524288
    float* out_attn = out + Bn * Sn * Hn;            // (B,S,S) = 1048576

    float* ws   = (float*)d_ws;
    float* Egt  = ws;                                 // 524288 f
    float* Egp4 = ws + 524288;                        // 524288 f
    float* wa2  = ws + 1048576;                       // 256 f
    float* cst  = ws + 1048832;                       // 1 f

    gemm_kernel<<<dim3(512), dim3(512), 0, stream>>>(
        h, Wt, Wtp, Wa, ba, bh, Egt, Egp4, wa2, cst);
    attn_kernel<<<dim3(Bn * (Sn / 2)), dim3(512), 0, stream>>>(
        h, Egt, Egp4, wa2, cst, out, out_attn);
}

// Round 6
// 112.056 us; speedup vs baseline: 1.0893x; 1.0893x over previous
//
#include <hip/hip_runtime.h>

// Problem constants: B=4, S=512, H=256
#define Bn 4
#define Sn 512
#define Hn 256

#define CC   2.8853900817779268f   // 2*log2(e)
#define L2E  1.4426950408889634f

typedef __attribute__((ext_vector_type(4))) float f32x4;
typedef __attribute__((ext_vector_type(8))) short short8;
typedef __attribute__((ext_vector_type(2))) float v2f;

__device__ __forceinline__ unsigned short bf16rn(float f) {
    unsigned int u = __float_as_uint(f);
    u += 0x7fffu + ((u >> 16) & 1u);
    return (unsigned short)(u >> 16);
}
__device__ __forceinline__ float bf16tof(unsigned short b) {
    return __uint_as_float(((unsigned int)b) << 16);
}

// ---------------------------------------------------------------------------
// gemm R16 + R21 layout permutation: within each k4-group, components are
// stored in order (0,2,1,3) in Egt / Egp4 / wa2 so that attn phase 1 can use
// v_pk_*_f32 packed math with zero repacking moves (pairs = load lo/hi).
// The 4-term rational combine is symmetric under within-group permutation.
// ---------------------------------------------------------------------------
__global__ __launch_bounds__(512, 4) void gemm_kernel(
    const float* __restrict__ h,  const float* __restrict__ Wt,
    const float* __restrict__ Wp, const float* __restrict__ Wa,
    const float* __restrict__ ba, const float* __restrict__ bh,
    float* __restrict__ Egt, float* __restrict__ Egp4,
    float* __restrict__ wa2, float* __restrict__ cst)
{
    // A1@0 A2@8704 (32x136 shorts) B1@17408 B2@34816 (64x136 shorts)
    // tile@52224 (32x68 f32; reused as ct) red4@60928
    __shared__ char lds[60944];
    unsigned short* A1 = (unsigned short*)lds;
    unsigned short* A2 = (unsigned short*)(lds + 8704);
    unsigned short* B1 = (unsigned short*)(lds + 17408);
    unsigned short* B2 = (unsigned short*)(lds + 34816);
    float* tile = (float*)(lds + 52224);
    float* red4 = (float*)(lds + 60928);

    const int tid = threadIdx.x;            // 0..511
    const int mb  = blockIdx.x >> 3;        // 0..63 (32-row m-tiles)
    const int nb  = blockIdx.x & 7;
    const int m0  = mb * 32;
    const bool isT = (nb < 4);
    const int n0  = (isT ? nb : nb - 4) * 64;
    const float* __restrict__ W = isT ? Wt : Wp;

    if (blockIdx.x == 0) {
        if (tid < 256) {
            float wv = Wa[tid];
#pragma unroll
            for (int off = 32; off >= 1; off >>= 1) wv += __shfl_xor(wv, off, 64);
            if ((tid & 63) == 0) red4[tid >> 6] = wv;
        }
        __syncthreads();
        if (tid < 256) {
            // permuted within group of 4: mem pos p holds orig j = {0,2,1,3}[p]
            const int p   = tid & 3;
            const int src = (tid & ~3) | (((p << 1) | (p >> 1)) & 3);
            wa2[tid] = -2.0f * Wa[src];
        }
        if (tid == 0)
            cst[0] = -L2E * ((red4[0] + red4[1] + red4[2] + red4[3]) + ba[0]);
    }

    const int w    = tid >> 6;              // 0..7
    const int w2   = w & 3;                 // n-quadrant
    const int mh   = w >> 2;                // m-half
    const int lane = tid & 63;
    const int quad = lane >> 4;
    const int l15  = lane & 15;

    f32x4 acc = (f32x4){0.f, 0.f, 0.f, 0.f};

    for (int kh2 = 0; kh2 < 2; kh2++) {
        const int K0 = kh2 << 7;
        __syncthreads();

        {
            const int row = tid >> 4;
            const int seg = (tid & 15) * 8;
            const float* __restrict__ src = h + (m0 + row) * Hn + K0 + seg;
            unsigned int* d1 = (unsigned int*)A1 + row * 68 + (seg >> 1);
            unsigned int* d2 = (unsigned int*)A2 + row * 68 + (seg >> 1);
#pragma unroll
            for (int i = 0; i < 2; i++) {
                const float4 v = ((const float4*)src)[i];
                const float f[4] = {v.x, v.y, v.z, v.w};
                unsigned short b1[4], b2[4];
#pragma unroll
                for (int j = 0; j < 4; j++) {
                    b1[j] = bf16rn(f[j]);
                    b2[j] = bf16rn(f[j] - bf16tof(b1[j]));
                }
                d1[2 * i]     = (unsigned)b1[0] | ((unsigned)b1[1] << 16);
                d1[2 * i + 1] = (unsigned)b1[2] | ((unsigned)b1[3] << 16);
                d2[2 * i]     = (unsigned)b2[0] | ((unsigned)b2[1] << 16);
                d2[2 * i + 1] = (unsigned)b2[2] | ((unsigned)b2[3] << 16);
            }
        }

        for (int kt = 0; kt < 4; kt++) {
            const int koff = K0 + kt * 32;
            if (kt) __syncthreads();
            {
                const int kr = tid >> 4;
                const int nq = tid & 15;
                *(float4*)&tile[kr * 68 + nq * 4] =
                    *(const float4*)&W[(koff + kr) * Hn + n0 + nq * 4];
            }
            __syncthreads();
            {
                const int n  = tid >> 3;
                const int p0 = (tid & 7) * 2;
                const float f0 = tile[(2 * p0    ) * 68 + n];
                const float f1 = tile[(2 * p0 + 1) * 68 + n];
                const float f2 = tile[(2 * p0 + 2) * 68 + n];
                const float f3 = tile[(2 * p0 + 3) * 68 + n];
                const unsigned short a0 = bf16rn(f0), a1 = bf16rn(f1);
                const unsigned short a2 = bf16rn(f2), a3 = bf16rn(f3);
                const unsigned short c0 = bf16rn(f0 - bf16tof(a0));
                const unsigned short c1 = bf16rn(f1 - bf16tof(a1));
                const unsigned short c2 = bf16rn(f2 - bf16tof(a2));
                const unsigned short c3 = bf16rn(f3 - bf16tof(a3));
                unsigned int* o1 = (unsigned int*)B1 + n * 68 + kt * 16 + p0;
                unsigned int* o2 = (unsigned int*)B2 + n * 68 + kt * 16 + p0;
                o1[0] = (unsigned)a0 | ((unsigned)a1 << 16);
                o1[1] = (unsigned)a2 | ((unsigned)a3 << 16);
                o2[0] = (unsigned)c0 | ((unsigned)c1 << 16);
                o2[1] = (unsigned)c2 | ((unsigned)c3 << 16);
            }
        }
        __syncthreads();

#pragma unroll
        for (int ks = 0; ks < 128; ks += 32) {
            const int bof = (w2 * 16 + l15) * 136 + ks + quad * 8;
            const short8 b1 = *(const short8*)(B1 + bof);
            const short8 b2 = *(const short8*)(B2 + bof);
            const int aof = (mh * 16 + l15) * 136 + ks + quad * 8;
            const short8 a1 = *(const short8*)(A1 + aof);
            const short8 a2 = *(const short8*)(A2 + aof);
            acc = __builtin_amdgcn_mfma_f32_16x16x32_bf16(a1, b1, acc, 0, 0, 0);
            acc = __builtin_amdgcn_mfma_f32_16x16x32_bf16(a1, b2, acc, 0, 0, 0);
            acc = __builtin_amdgcn_mfma_f32_16x16x32_bf16(a2, b1, acc, 0, 0, 0);
        }
    }

    float* ct = tile;
#pragma unroll
    for (int r = 0; r < 4; r++)
        ct[(mh * 16 + quad * 4 + r) * 68 + w2 * 16 + l15] = acc[r];
    __syncthreads();

    const int b  = m0 >> 9;
    const int s0 = m0 & 511;
    if (isT) {
        const int n0g = nb * 64;
        const int mr = tid >> 4, nq = tid & 15;
        const float4 c  = *(const float4*)&ct[mr * 68 + nq * 4];
        const float4 bv = *(const float4*)&bh[n0g + nq * 4];
        // permuted store: mem (x,y,z,w) <- orig (0,2,1,3)
        float4 o;
        o.x = __builtin_amdgcn_exp2f((c.x + bv.x) * CC);
        o.y = __builtin_amdgcn_exp2f((c.z + bv.z) * CC);
        o.z = __builtin_amdgcn_exp2f((c.y + bv.y) * CC);
        o.w = __builtin_amdgcn_exp2f((c.w + bv.w) * CC);
        *(float4*)&Egt[(m0 + mr) * Hn + n0g + nq * 4] = o;
    } else {
        const int kq0 = (nb - 4) * 16;
        const int mr = tid & 31, nq = tid >> 5;
        const float4 c = *(const float4*)&ct[mr * 68 + nq * 4];
        // permuted store: mem (x,y,z,w) <- orig (0,2,1,3)
        float4 o;
        o.x = __builtin_amdgcn_exp2f(c.x * CC);
        o.y = __builtin_amdgcn_exp2f(c.z * CC);
        o.z = __builtin_amdgcn_exp2f(c.y * CC);
        o.w = __builtin_amdgcn_exp2f(c.w * CC);
        *(float4*)&Egp4[b * 131072 + (kq0 + nq) * 2048 + (s0 + mr) * 4] = o;
    }
}

// ---------------------------------------------------------------------------
// attn R21: R18 structure (46.3us best) with phase-1 math in packed fp32.
// Producers store each k4-group's components in order (0,2,1,3), so:
//   cur = (c1,c3,c2,c4) -> ca=(c1,c3), cb=(c2,c4)  [load lo/hi, no movs]
//   Da = ca*ea+1 = (d1,d3); Db = (d2,d4)           [2 v_pk_fma_f32]
//   P  = Da*Db = (p12,p34)                         [1 v_pk_mul_f32]
//   N  = wa*Db + wb*Da = (n12,n34)                 [pk_mul + pk_fma]
//   num/den/rcp/acc scalar                         [4 + rcp]
// 10 issues vs 14 per (row,group) -> ~29% off the dominant VALU cost.
// Identical math set per group (permutation-symmetric 4-term combine).
// ---------------------------------------------------------------------------
__global__ __launch_bounds__(1024) void attn_kernel(
    const float* __restrict__ hsrc, const float* __restrict__ Egt,
    const float* __restrict__ Egp4, const float* __restrict__ wa2,
    const float* __restrict__ cst,
    float* __restrict__ out, float* __restrict__ out_attn)
{
    // [0,8K) attn_l[4][512] ; [8K,16K) accl[4][512] ; [16K,16.25K) red ;
    // part[8][4][64]f4 32KB aliases [8K,40K) (phase 2 only; accl/red dead)
    __shared__ char smem[40960];
    float*  attn_l = (float*)smem;
    float*  accl   = (float*)(smem + 8192);
    float*  red    = (float*)(smem + 16384);
    float4* part   = (float4*)(smem + 8192);

    const int tid = threadIdx.x;       // 0..1023
    const int tp  = tid & 511;
    const int kh  = tid >> 9;          // 0 or 1: k-half (wave-uniform)
    const int b   = blockIdx.x & 3;
    const int t0  = (blockIdx.x >> 2) << 2;

    const int kbu = __builtin_amdgcn_readfirstlane(kh << 5);

    const float* __restrict__ egt = Egt + (b * Sn + t0) * Hn;   // block-uniform
    const float4* __restrict__ ep = (const float4*)(Egp4 + b * (Hn * Sn));

    float acc[4] = {0.f, 0.f, 0.f, 0.f};

    float4 w4c  = *(const float4*)&wa2[kbu * 4];
    float4 eg0c = *(const float4*)&egt[0 * Hn + kbu * 4];
    float4 eg1c = *(const float4*)&egt[1 * Hn + kbu * 4];
    float4 eg2c = *(const float4*)&egt[2 * Hn + kbu * 4];
    float4 eg3c = *(const float4*)&egt[3 * Hn + kbu * 4];

    const v2f one2 = (v2f){1.0f, 1.0f};

#pragma unroll 2
    for (int kk = 0; kk < 32; kk++) {
        const int k4n = kbu + ((kk + 1) & 31);
        const float4 w4n  = *(const float4*)&wa2[k4n * 4];
        const float4 eg0n = *(const float4*)&egt[0 * Hn + k4n * 4];
        const float4 eg1n = *(const float4*)&egt[1 * Hn + k4n * 4];
        const float4 eg2n = *(const float4*)&egt[2 * Hn + k4n * 4];
        const float4 eg3n = *(const float4*)&egt[3 * Hn + k4n * 4];

        const float4 cur = ep[(kbu + kk) * Sn + tp];   // coalesced vector load
        const v2f ca = (v2f){cur.x, cur.y};            // (c1,c3) — lo half
        const v2f cb = (v2f){cur.z, cur.w};            // (c2,c4) — hi half
        const v2f wa = (v2f){w4c.x, w4c.y};            // (w1,w3)
        const v2f wb = (v2f){w4c.z, w4c.w};            // (w2,w4)

        const float4 egs[4] = {eg0c, eg1c, eg2c, eg3c};
#pragma unroll
        for (int r = 0; r < 4; r++) {
            const float4 eg = egs[r];
            const v2f ea = (v2f){eg.x, eg.y};          // (e1,e3)
            const v2f eb = (v2f){eg.z, eg.w};          // (e2,e4)
            const v2f Da = __builtin_elementwise_fma(ca, ea, one2); // (d1,d3)
            const v2f Db = __builtin_elementwise_fma(cb, eb, one2); // (d2,d4)
            const v2f P  = Da * Db;                                 // (p12,p34)
            const v2f N  = __builtin_elementwise_fma(wa, Db, wb * Da); // (n12,n34)
            const float num = fmaf(N.x, P.y, N.y * P.x);
            acc[r] = fmaf(num, __builtin_amdgcn_rcpf(P.x * P.y), acc[r]);
        }

        w4c = w4n; eg0c = eg0n; eg1c = eg1n; eg2c = eg2n; eg3c = eg3n;
    }

    // ---- cross-half exchange: kh1 shares rows 0-1, kh0 shares rows 2-3 ----
    if (kh == 1) {
        accl[0 * 512 + tp] = acc[0];
        accl[1 * 512 + tp] = acc[1];
    } else {
        accl[2 * 512 + tp] = acc[2];
        accl[3 * 512 + tp] = acc[3];
    }
    __syncthreads();

    // ---- softmax: kh0 handles rows 0-1, kh1 handles rows 2-3 ----
    float ex[2];
    const float k0 = cst[0];
    const int  r0 = kh << 1;
    {
#pragma unroll
        for (int i = 0; i < 2; i++) {
            const int r = r0 + i;
            const float a   = acc[r] + accl[r * 512 + tp];
            const float e1  = __builtin_amdgcn_exp2f(fmaf(-L2E, a, k0));
            const float sig = __builtin_amdgcn_rcpf(1.0f + e1);
            ex[i] = __builtin_amdgcn_exp2f(L2E * sig);
        }
        const int lane = tid & 63, widl = (tid >> 6) & 7;
#pragma unroll
        for (int i = 0; i < 2; i++) {
            float v = ex[i];
#pragma unroll
            for (int off = 32; off >= 1; off >>= 1) v += __shfl_xor(v, off, 64);
            if (lane == 0) red[(r0 + i) * 8 + widl] = v;
        }
    }
    __syncthreads();

    {
#pragma unroll
        for (int i = 0; i < 2; i++) {
            const int r = r0 + i;
            float tot = 0.f;
#pragma unroll
            for (int j = 0; j < 8; j++) tot += red[r * 8 + j];
            const float a = ex[i] * __builtin_amdgcn_rcpf(tot);
            attn_l[r * Sn + tp] = a;
            out_attn[(b * Sn + t0 + r) * Sn + tp] = a;
        }
    }
    __syncthreads();

    // ---- phase 2: out rows = attn @ h. 16 q-groups of 32 t' each ----
    const int c4 = tid & 63;
    const int q  = tid >> 6;                 // 0..15, wave-uniform

    const float* __restrict__ hb = hsrc + (b * Sn + q * 32) * Hn + c4 * 4;

    float4 a4[4];
#pragma unroll
    for (int r = 0; r < 4; r++) a4[r] = (float4){0.f, 0.f, 0.f, 0.f};

#pragma unroll 2
    for (int j4 = 0; j4 < 8; j4++) {
        float4 wv[4];
#pragma unroll
        for (int r = 0; r < 4; r++)
            wv[r] = *(const float4*)&attn_l[r * Sn + q * 32 + j4 * 4];  // bcast
#pragma unroll
        for (int i = 0; i < 4; i++) {
            const float4 hv = *(const float4*)&hb[(j4 * 4 + i) * Hn];
#pragma unroll
            for (int r = 0; r < 4; r++) {
                const float wr = ((const float*)&wv[r])[i];
                a4[r].x = fmaf(wr, hv.x, a4[r].x);
                a4[r].y = fmaf(wr, hv.y, a4[r].y);
                a4[r].z = fmaf(wr, hv.z, a4[r].z);
                a4[r].w = fmaf(wr, hv.w, a4[r].w);
            }
        }
    }
    __syncthreads();   // accl/red reads all done; part may now alias

    if (q < 8) {
#pragma unroll
        for (int r = 0; r < 4; r++) part[(q * 4 + r) * 64 + c4] = a4[r];
    }
    __syncthreads();
    if (q >= 8) {
#pragma unroll
        for (int r = 0; r < 4; r++) {
            float4 p = part[((q - 8) * 4 + r) * 64 + c4];
            p.x += a4[r].x; p.y += a4[r].y; p.z += a4[r].z; p.w += a4[r].w;
            part[((q - 8) * 4 + r) * 64 + c4] = p;
        }
    }
    __syncthreads();

    // final: 1024 threads = 256 cols x 4 rows; sum the 8 q-partials
    {
        const int col = tid & 255;
        const int r   = tid >> 8;
        const float* pf = (const float*)part;
        float s = 0.f;
#pragma unroll
        for (int qq = 0; qq < 8; qq++)
            s += pf[((qq * 4 + r) * 64 + (col >> 2)) * 4 + (col & 3)];
        out[(b * Sn + t0 + r) * Hn + col] = s;
    }
}

extern "C" void kernel_launch(void* const* d_in, const int* in_sizes, int n_in,
                              void* d_out, int out_size, void* d_ws, size_t ws_size,
                              hipStream_t stream) {
    const float* h   = (const float*)d_in[0];
    const float* Wt  = (const float*)d_in[1];
    const float* Wtp = (const float*)d_in[2];
    const float* bh  = (const float*)d_in[3];
    const float* Wa  = (const float*)d_in[4];
    const float* ba  = (const float*)d_in[5];

    float* out      = (float*)d_out;                 // (B,S,H) = 524288
    float* out_attn = out + Bn * Sn * Hn;            // (B,S,S) = 1048576

    float* ws   = (float*)d_ws;
    float* Egt  = ws;                                 // 524288 f
    float* Egp4 = ws + 524288;                        // 524288 f
    float* wa2  = ws + 1048576;                       // 256 f
    float* cst  = ws + 1048832;                       // 1 f

    gemm_kernel<<<dim3(512), dim3(512), 0, stream>>>(
        h, Wt, Wtp, Wa, ba, bh, Egt, Egp4, wa2, cst);
    attn_kernel<<<dim3(Bn * (Sn / 4)), dim3(1024), 0, stream>>>(
        h, Egt, Egp4, wa2, cst, out, out_attn);
}

// Round 7
// 108.540 us; speedup vs baseline: 1.1246x; 1.0324x over previous
//
#include <hip/hip_runtime.h>

// Problem constants: B=4, S=512, H=256
#define Bn 4
#define Sn 512
#define Hn 256

#define CC   2.8853900817779268f   // 2*log2(e)
#define L2E  1.4426950408889634f

typedef __attribute__((ext_vector_type(4))) float f32x4;
typedef __attribute__((ext_vector_type(8))) short short8;

__device__ __forceinline__ unsigned short bf16rn(float f) {
    unsigned int u = __float_as_uint(f);
    u += 0x7fffu + ((u >> 16) & 1u);
    return (unsigned short)(u >> 16);
}
__device__ __forceinline__ float bf16tof(unsigned short b) {
    return __uint_as_float(((unsigned int)b) << 16);
}

// ---------------------------------------------------------------------------
// gemm R21 (kept verbatim): R16 structure + (0,2,1,3) within-group layout
// permutation in Egt/Egp4/wa2 (proven bit-identical at the consumer).
// ---------------------------------------------------------------------------
__global__ __launch_bounds__(512, 4) void gemm_kernel(
    const float* __restrict__ h,  const float* __restrict__ Wt,
    const float* __restrict__ Wp, const float* __restrict__ Wa,
    const float* __restrict__ ba, const float* __restrict__ bh,
    float* __restrict__ Egt, float* __restrict__ Egp4,
    float* __restrict__ wa2, float* __restrict__ cst)
{
    // A1@0 A2@8704 (32x136 shorts) B1@17408 B2@34816 (64x136 shorts)
    // tile@52224 (32x68 f32; reused as ct) red4@60928
    __shared__ char lds[60944];
    unsigned short* A1 = (unsigned short*)lds;
    unsigned short* A2 = (unsigned short*)(lds + 8704);
    unsigned short* B1 = (unsigned short*)(lds + 17408);
    unsigned short* B2 = (unsigned short*)(lds + 34816);
    float* tile = (float*)(lds + 52224);
    float* red4 = (float*)(lds + 60928);

    const int tid = threadIdx.x;            // 0..511
    const int mb  = blockIdx.x >> 3;        // 0..63 (32-row m-tiles)
    const int nb  = blockIdx.x & 7;
    const int m0  = mb * 32;
    const bool isT = (nb < 4);
    const int n0  = (isT ? nb : nb - 4) * 64;
    const float* __restrict__ W = isT ? Wt : Wp;

    if (blockIdx.x == 0) {
        if (tid < 256) {
            float wv = Wa[tid];
#pragma unroll
            for (int off = 32; off >= 1; off >>= 1) wv += __shfl_xor(wv, off, 64);
            if ((tid & 63) == 0) red4[tid >> 6] = wv;
        }
        __syncthreads();
        if (tid < 256) {
            // permuted within group of 4: mem pos p holds orig j = {0,2,1,3}[p]
            const int p   = tid & 3;
            const int src = (tid & ~3) | (((p << 1) | (p >> 1)) & 3);
            wa2[tid] = -2.0f * Wa[src];
        }
        if (tid == 0)
            cst[0] = -L2E * ((red4[0] + red4[1] + red4[2] + red4[3]) + ba[0]);
    }

    const int w    = tid >> 6;              // 0..7
    const int w2   = w & 3;                 // n-quadrant
    const int mh   = w >> 2;                // m-half
    const int lane = tid & 63;
    const int quad = lane >> 4;
    const int l15  = lane & 15;

    f32x4 acc = (f32x4){0.f, 0.f, 0.f, 0.f};

    for (int kh2 = 0; kh2 < 2; kh2++) {
        const int K0 = kh2 << 7;
        __syncthreads();

        {
            const int row = tid >> 4;
            const int seg = (tid & 15) * 8;
            const float* __restrict__ src = h + (m0 + row) * Hn + K0 + seg;
            unsigned int* d1 = (unsigned int*)A1 + row * 68 + (seg >> 1);
            unsigned int* d2 = (unsigned int*)A2 + row * 68 + (seg >> 1);
#pragma unroll
            for (int i = 0; i < 2; i++) {
                const float4 v = ((const float4*)src)[i];
                const float f[4] = {v.x, v.y, v.z, v.w};
                unsigned short b1[4], b2[4];
#pragma unroll
                for (int j = 0; j < 4; j++) {
                    b1[j] = bf16rn(f[j]);
                    b2[j] = bf16rn(f[j] - bf16tof(b1[j]));
                }
                d1[2 * i]     = (unsigned)b1[0] | ((unsigned)b1[1] << 16);
                d1[2 * i + 1] = (unsigned)b1[2] | ((unsigned)b1[3] << 16);
                d2[2 * i]     = (unsigned)b2[0] | ((unsigned)b2[1] << 16);
                d2[2 * i + 1] = (unsigned)b2[2] | ((unsigned)b2[3] << 16);
            }
        }

        for (int kt = 0; kt < 4; kt++) {
            const int koff = K0 + kt * 32;
            if (kt) __syncthreads();
            {
                const int kr = tid >> 4;
                const int nq = tid & 15;
                *(float4*)&tile[kr * 68 + nq * 4] =
                    *(const float4*)&W[(koff + kr) * Hn + n0 + nq * 4];
            }
            __syncthreads();
            {
                const int n  = tid >> 3;
                const int p0 = (tid & 7) * 2;
                const float f0 = tile[(2 * p0    ) * 68 + n];
                const float f1 = tile[(2 * p0 + 1) * 68 + n];
                const float f2 = tile[(2 * p0 + 2) * 68 + n];
                const float f3 = tile[(2 * p0 + 3) * 68 + n];
                const unsigned short a0 = bf16rn(f0), a1 = bf16rn(f1);
                const unsigned short a2 = bf16rn(f2), a3 = bf16rn(f3);
                const unsigned short c0 = bf16rn(f0 - bf16tof(a0));
                const unsigned short c1 = bf16rn(f1 - bf16tof(a1));
                const unsigned short c2 = bf16rn(f2 - bf16tof(a2));
                const unsigned short c3 = bf16rn(f3 - bf16tof(a3));
                unsigned int* o1 = (unsigned int*)B1 + n * 68 + kt * 16 + p0;
                unsigned int* o2 = (unsigned int*)B2 + n * 68 + kt * 16 + p0;
                o1[0] = (unsigned)a0 | ((unsigned)a1 << 16);
                o1[1] = (unsigned)a2 | ((unsigned)a3 << 16);
                o2[0] = (unsigned)c0 | ((unsigned)c1 << 16);
                o2[1] = (unsigned)c2 | ((unsigned)c3 << 16);
            }
        }
        __syncthreads();

#pragma unroll
        for (int ks = 0; ks < 128; ks += 32) {
            const int bof = (w2 * 16 + l15) * 136 + ks + quad * 8;
            const short8 b1 = *(const short8*)(B1 + bof);
            const short8 b2 = *(const short8*)(B2 + bof);
            const int aof = (mh * 16 + l15) * 136 + ks + quad * 8;
            const short8 a1 = *(const short8*)(A1 + aof);
            const short8 a2 = *(const short8*)(A2 + aof);
            acc = __builtin_amdgcn_mfma_f32_16x16x32_bf16(a1, b1, acc, 0, 0, 0);
            acc = __builtin_amdgcn_mfma_f32_16x16x32_bf16(a1, b2, acc, 0, 0, 0);
            acc = __builtin_amdgcn_mfma_f32_16x16x32_bf16(a2, b1, acc, 0, 0, 0);
        }
    }

    float* ct = tile;
#pragma unroll
    for (int r = 0; r < 4; r++)
        ct[(mh * 16 + quad * 4 + r) * 68 + w2 * 16 + l15] = acc[r];
    __syncthreads();

    const int b  = m0 >> 9;
    const int s0 = m0 & 511;
    if (isT) {
        const int n0g = nb * 64;
        const int mr = tid >> 4, nq = tid & 15;
        const float4 c  = *(const float4*)&ct[mr * 68 + nq * 4];
        const float4 bv = *(const float4*)&bh[n0g + nq * 4];
        // permuted store: mem (x,y,z,w) <- orig (0,2,1,3)
        float4 o;
        o.x = __builtin_amdgcn_exp2f((c.x + bv.x) * CC);
        o.y = __builtin_amdgcn_exp2f((c.z + bv.z) * CC);
        o.z = __builtin_amdgcn_exp2f((c.y + bv.y) * CC);
        o.w = __builtin_amdgcn_exp2f((c.w + bv.w) * CC);
        *(float4*)&Egt[(m0 + mr) * Hn + n0g + nq * 4] = o;
    } else {
        const int kq0 = (nb - 4) * 16;
        const int mr = tid & 31, nq = tid >> 5;
        const float4 c = *(const float4*)&ct[mr * 68 + nq * 4];
        // permuted store: mem (x,y,z,w) <- orig (0,2,1,3)
        float4 o;
        o.x = __builtin_amdgcn_exp2f(c.x * CC);
        o.y = __builtin_amdgcn_exp2f(c.z * CC);
        o.z = __builtin_amdgcn_exp2f(c.y * CC);
        o.w = __builtin_amdgcn_exp2f(c.w * CC);
        *(float4*)&Egp4[b * 131072 + (kq0 + nq) * 2048 + (s0 + mr) * 4] = o;
    }
}

// ---------------------------------------------------------------------------
// attn R22: R21 structure with the phase-1 body de-arrayed. R18/R21 built
// `const float4 egs[4] = {eg0c,...}` (+ R21's v2f temps) each iteration —
// the eg/w4 operands are SGPR-resident (s_load pipeline), and the array/
// vector construction plausibly forces ~16 S->V v_movs per kk: exactly the
// ~17/kk non-math VALU overhead fitted from R18-vs-R20 busy-times. Fix:
// four explicit per-row expansions whose fmas reference eg fields directly
// (v_fma can read 1 SGPR operand inline). Op sequence is the exact scalar
// expansion of R21's packed form -> bit-identical results.
// ---------------------------------------------------------------------------
__global__ __launch_bounds__(1024) void attn_kernel(
    const float* __restrict__ hsrc, const float* __restrict__ Egt,
    const float* __restrict__ Egp4, const float* __restrict__ wa2,
    const float* __restrict__ cst,
    float* __restrict__ out, float* __restrict__ out_attn)
{
    // [0,8K) attn_l[4][512] ; [8K,16K) accl[4][512] ; [16K,16.25K) red ;
    // part[8][4][64]f4 32KB aliases [8K,40K) (phase 2 only; accl/red dead)
    __shared__ char smem[40960];
    float*  attn_l = (float*)smem;
    float*  accl   = (float*)(smem + 8192);
    float*  red    = (float*)(smem + 16384);
    float4* part   = (float4*)(smem + 8192);

    const int tid = threadIdx.x;       // 0..1023
    const int tp  = tid & 511;
    const int kh  = tid >> 9;          // 0 or 1: k-half (wave-uniform)
    const int b   = blockIdx.x & 3;
    const int t0  = (blockIdx.x >> 2) << 2;

    const int kbu = __builtin_amdgcn_readfirstlane(kh << 5);

    const float* __restrict__ egt = Egt + (b * Sn + t0) * Hn;   // block-uniform
    const float4* __restrict__ ep = (const float4*)(Egp4 + b * (Hn * Sn));

    float acc0 = 0.f, acc1 = 0.f, acc2 = 0.f, acc3 = 0.f;

    float4 w4c  = *(const float4*)&wa2[kbu * 4];
    float4 eg0c = *(const float4*)&egt[0 * Hn + kbu * 4];
    float4 eg1c = *(const float4*)&egt[1 * Hn + kbu * 4];
    float4 eg2c = *(const float4*)&egt[2 * Hn + kbu * 4];
    float4 eg3c = *(const float4*)&egt[3 * Hn + kbu * 4];

    // Exact scalar expansion of R21's packed body; eg/w4 fields referenced
    // directly so VALU ops take the SGPR operand inline (no S->V copies).
#define P1ROW(EG, ACC)                                                        \
    {                                                                         \
        const float d0 = fmaf(cur.x, EG.x, 1.0f);                             \
        const float d1 = fmaf(cur.y, EG.y, 1.0f);                             \
        const float d2 = fmaf(cur.z, EG.z, 1.0f);                             \
        const float d3 = fmaf(cur.w, EG.w, 1.0f);                             \
        const float p0 = d0 * d2;                                             \
        const float p1 = d1 * d3;                                             \
        const float n0 = fmaf(w4c.x, d2, w4c.z * d0);                         \
        const float n1 = fmaf(w4c.y, d3, w4c.w * d1);                         \
        const float num = fmaf(n0, p1, n1 * p0);                              \
        ACC = fmaf(num, __builtin_amdgcn_rcpf(p0 * p1), ACC);                 \
    }

#pragma unroll 2
    for (int kk = 0; kk < 32; kk++) {
        const int k4n = kbu + ((kk + 1) & 31);
        const float4 w4n  = *(const float4*)&wa2[k4n * 4];
        const float4 eg0n = *(const float4*)&egt[0 * Hn + k4n * 4];
        const float4 eg1n = *(const float4*)&egt[1 * Hn + k4n * 4];
        const float4 eg2n = *(const float4*)&egt[2 * Hn + k4n * 4];
        const float4 eg3n = *(const float4*)&egt[3 * Hn + k4n * 4];

        const float4 cur = ep[(kbu + kk) * Sn + tp];   // coalesced vector load

        P1ROW(eg0c, acc0)
        P1ROW(eg1c, acc1)
        P1ROW(eg2c, acc2)
        P1ROW(eg3c, acc3)

        w4c = w4n; eg0c = eg0n; eg1c = eg1n; eg2c = eg2n; eg3c = eg3n;
    }
#undef P1ROW

    float acc[4] = {acc0, acc1, acc2, acc3};

    // ---- cross-half exchange: kh1 shares rows 0-1, kh0 shares rows 2-3 ----
    if (kh == 1) {
        accl[0 * 512 + tp] = acc[0];
        accl[1 * 512 + tp] = acc[1];
    } else {
        accl[2 * 512 + tp] = acc[2];
        accl[3 * 512 + tp] = acc[3];
    }
    __syncthreads();

    // ---- softmax: kh0 handles rows 0-1, kh1 handles rows 2-3 ----
    float ex[2];
    const float k0 = cst[0];
    const int  r0 = kh << 1;
    {
#pragma unroll
        for (int i = 0; i < 2; i++) {
            const int r = r0 + i;
            const float a   = acc[r] + accl[r * 512 + tp];
            const float e1  = __builtin_amdgcn_exp2f(fmaf(-L2E, a, k0));
            const float sig = __builtin_amdgcn_rcpf(1.0f + e1);
            ex[i] = __builtin_amdgcn_exp2f(L2E * sig);
        }
        const int lane = tid & 63, widl = (tid >> 6) & 7;
#pragma unroll
        for (int i = 0; i < 2; i++) {
            float v = ex[i];
#pragma unroll
            for (int off = 32; off >= 1; off >>= 1) v += __shfl_xor(v, off, 64);
            if (lane == 0) red[(r0 + i) * 8 + widl] = v;
        }
    }
    __syncthreads();

    {
#pragma unroll
        for (int i = 0; i < 2; i++) {
            const int r = r0 + i;
            float tot = 0.f;
#pragma unroll
            for (int j = 0; j < 8; j++) tot += red[r * 8 + j];
            const float a = ex[i] * __builtin_amdgcn_rcpf(tot);
            attn_l[r * Sn + tp] = a;
            out_attn[(b * Sn + t0 + r) * Sn + tp] = a;
        }
    }
    __syncthreads();

    // ---- phase 2: out rows = attn @ h. 16 q-groups of 32 t' each ----
    const int c4 = tid & 63;
    const int q  = tid >> 6;                 // 0..15, wave-uniform

    const float* __restrict__ hb = hsrc + (b * Sn + q * 32) * Hn + c4 * 4;

    float4 a4[4];
#pragma unroll
    for (int r = 0; r < 4; r++) a4[r] = (float4){0.f, 0.f, 0.f, 0.f};

#pragma unroll 2
    for (int j4 = 0; j4 < 8; j4++) {
        float4 wv[4];
#pragma unroll
        for (int r = 0; r < 4; r++)
            wv[r] = *(const float4*)&attn_l[r * Sn + q * 32 + j4 * 4];  // bcast
#pragma unroll
        for (int i = 0; i < 4; i++) {
            const float4 hv = *(const float4*)&hb[(j4 * 4 + i) * Hn];
#pragma unroll
            for (int r = 0; r < 4; r++) {
                const float wr = ((const float*)&wv[r])[i];
                a4[r].x = fmaf(wr, hv.x, a4[r].x);
                a4[r].y = fmaf(wr, hv.y, a4[r].y);
                a4[r].z = fmaf(wr, hv.z, a4[r].z);
                a4[r].w = fmaf(wr, hv.w, a4[r].w);
            }
        }
    }
    __syncthreads();   // accl/red reads all done; part may now alias

    if (q < 8) {
#pragma unroll
        for (int r = 0; r < 4; r++) part[(q * 4 + r) * 64 + c4] = a4[r];
    }
    __syncthreads();
    if (q >= 8) {
#pragma unroll
        for (int r = 0; r < 4; r++) {
            float4 p = part[((q - 8) * 4 + r) * 64 + c4];
            p.x += a4[r].x; p.y += a4[r].y; p.z += a4[r].z; p.w += a4[r].w;
            part[((q - 8) * 4 + r) * 64 + c4] = p;
        }
    }
    __syncthreads();

    // final: 1024 threads = 256 cols x 4 rows; sum the 8 q-partials
    {
        const int col = tid & 255;
        const int r   = tid >> 8;
        const float* pf = (const float*)part;
        float s = 0.f;
#pragma unroll
        for (int qq = 0; qq < 8; qq++)
            s += pf[((qq * 4 + r) * 64 + (col >> 2)) * 4 + (col & 3)];
        out[(b * Sn + t0 + r) * Hn + col] = s;
    }
}

extern "C" void kernel_launch(void* const* d_in, const int* in_sizes, int n_in,
                              void* d_out, int out_size, void* d_ws, size_t ws_size,
                              hipStream_t stream) {
    const float* h   = (const float*)d_in[0];
    const float* Wt  = (const float*)d_in[1];
    const float* Wtp = (const float*)d_in[2];
    const float* bh  = (const float*)d_in[3];
    const float* Wa  = (const float*)d_in[4];
    const float* ba  = (const float*)d_in[5];

    float* out      = (float*)d_out;                 // (B,S,H) = 524288
    float* out_attn = out + Bn * Sn * Hn;            // (B,S,S) = 1048576

    float* ws   = (float*)d_ws;
    float* Egt  = ws;                                 // 524288 f
    float* Egp4 = ws + 524288;                        // 524288 f
    float* wa2  = ws + 1048576;                       // 256 f
    float* cst  = ws + 1048832;                       // 1 f

    gemm_kernel<<<dim3(512), dim3(512), 0, stream>>>(
        h, Wt, Wtp, Wa, ba, bh, Egt, Egp4, wa2, cst);
    attn_kernel<<<dim3(Bn * (Sn / 4)), dim3(1024), 0, stream>>>(
        h, Egt, Egp4, wa2, cst, out, out_attn);
}

// Round 8
// 108.039 us; speedup vs baseline: 1.1298x; 1.0046x over previous
//
#include <hip/hip_runtime.h>

// Problem constants: B=4, S=512, H=256
#define Bn 4
#define Sn 512
#define Hn 256

#define CC   2.8853900817779268f   // 2*log2(e)
#define L2E  1.4426950408889634f

typedef __attribute__((ext_vector_type(4))) float f32x4;
typedef __attribute__((ext_vector_type(8))) short short8;

__device__ __forceinline__ unsigned short bf16rn(float f) {
    unsigned int u = __float_as_uint(f);
    u += 0x7fffu + ((u >> 16) & 1u);
    return (unsigned short)(u >> 16);
}
__device__ __forceinline__ float bf16tof(unsigned short b) {
    return __uint_as_float(((unsigned int)b) << 16);
}

// ---------------------------------------------------------------------------
// gemm (kept verbatim): R16 structure + (0,2,1,3) within-group layout
// permutation in Egt/Egp4/wa2 (proven bit-identical at the consumer).
// ---------------------------------------------------------------------------
__global__ __launch_bounds__(512, 4) void gemm_kernel(
    const float* __restrict__ h,  const float* __restrict__ Wt,
    const float* __restrict__ Wp, const float* __restrict__ Wa,
    const float* __restrict__ ba, const float* __restrict__ bh,
    float* __restrict__ Egt, float* __restrict__ Egp4,
    float* __restrict__ wa2, float* __restrict__ cst)
{
    // A1@0 A2@8704 (32x136 shorts) B1@17408 B2@34816 (64x136 shorts)
    // tile@52224 (32x68 f32; reused as ct) red4@60928
    __shared__ char lds[60944];
    unsigned short* A1 = (unsigned short*)lds;
    unsigned short* A2 = (unsigned short*)(lds + 8704);
    unsigned short* B1 = (unsigned short*)(lds + 17408);
    unsigned short* B2 = (unsigned short*)(lds + 34816);
    float* tile = (float*)(lds + 52224);
    float* red4 = (float*)(lds + 60928);

    const int tid = threadIdx.x;            // 0..511
    const int mb  = blockIdx.x >> 3;        // 0..63 (32-row m-tiles)
    const int nb  = blockIdx.x & 7;
    const int m0  = mb * 32;
    const bool isT = (nb < 4);
    const int n0  = (isT ? nb : nb - 4) * 64;
    const float* __restrict__ W = isT ? Wt : Wp;

    if (blockIdx.x == 0) {
        if (tid < 256) {
            float wv = Wa[tid];
#pragma unroll
            for (int off = 32; off >= 1; off >>= 1) wv += __shfl_xor(wv, off, 64);
            if ((tid & 63) == 0) red4[tid >> 6] = wv;
        }
        __syncthreads();
        if (tid < 256) {
            // permuted within group of 4: mem pos p holds orig j = {0,2,1,3}[p]
            const int p   = tid & 3;
            const int src = (tid & ~3) | (((p << 1) | (p >> 1)) & 3);
            wa2[tid] = -2.0f * Wa[src];
        }
        if (tid == 0)
            cst[0] = -L2E * ((red4[0] + red4[1] + red4[2] + red4[3]) + ba[0]);
    }

    const int w    = tid >> 6;              // 0..7
    const int w2   = w & 3;                 // n-quadrant
    const int mh   = w >> 2;                // m-half
    const int lane = tid & 63;
    const int quad = lane >> 4;
    const int l15  = lane & 15;

    f32x4 acc = (f32x4){0.f, 0.f, 0.f, 0.f};

    for (int kh2 = 0; kh2 < 2; kh2++) {
        const int K0 = kh2 << 7;
        __syncthreads();

        {
            const int row = tid >> 4;
            const int seg = (tid & 15) * 8;
            const float* __restrict__ src = h + (m0 + row) * Hn + K0 + seg;
            unsigned int* d1 = (unsigned int*)A1 + row * 68 + (seg >> 1);
            unsigned int* d2 = (unsigned int*)A2 + row * 68 + (seg >> 1);
#pragma unroll
            for (int i = 0; i < 2; i++) {
                const float4 v = ((const float4*)src)[i];
                const float f[4] = {v.x, v.y, v.z, v.w};
                unsigned short b1[4], b2[4];
#pragma unroll
                for (int j = 0; j < 4; j++) {
                    b1[j] = bf16rn(f[j]);
                    b2[j] = bf16rn(f[j] - bf16tof(b1[j]));
                }
                d1[2 * i]     = (unsigned)b1[0] | ((unsigned)b1[1] << 16);
                d1[2 * i + 1] = (unsigned)b1[2] | ((unsigned)b1[3] << 16);
                d2[2 * i]     = (unsigned)b2[0] | ((unsigned)b2[1] << 16);
                d2[2 * i + 1] = (unsigned)b2[2] | ((unsigned)b2[3] << 16);
            }
        }

        for (int kt = 0; kt < 4; kt++) {
            const int koff = K0 + kt * 32;
            if (kt) __syncthreads();
            {
                const int kr = tid >> 4;
                const int nq = tid & 15;
                *(float4*)&tile[kr * 68 + nq * 4] =
                    *(const float4*)&W[(koff + kr) * Hn + n0 + nq * 4];
            }
            __syncthreads();
            {
                const int n  = tid >> 3;
                const int p0 = (tid & 7) * 2;
                const float f0 = tile[(2 * p0    ) * 68 + n];
                const float f1 = tile[(2 * p0 + 1) * 68 + n];
                const float f2 = tile[(2 * p0 + 2) * 68 + n];
                const float f3 = tile[(2 * p0 + 3) * 68 + n];
                const unsigned short a0 = bf16rn(f0), a1 = bf16rn(f1);
                const unsigned short a2 = bf16rn(f2), a3 = bf16rn(f3);
                const unsigned short c0 = bf16rn(f0 - bf16tof(a0));
                const unsigned short c1 = bf16rn(f1 - bf16tof(a1));
                const unsigned short c2 = bf16rn(f2 - bf16tof(a2));
                const unsigned short c3 = bf16rn(f3 - bf16tof(a3));
                unsigned int* o1 = (unsigned int*)B1 + n * 68 + kt * 16 + p0;
                unsigned int* o2 = (unsigned int*)B2 + n * 68 + kt * 16 + p0;
                o1[0] = (unsigned)a0 | ((unsigned)a1 << 16);
                o1[1] = (unsigned)a2 | ((unsigned)a3 << 16);
                o2[0] = (unsigned)c0 | ((unsigned)c1 << 16);
                o2[1] = (unsigned)c2 | ((unsigned)c3 << 16);
            }
        }
        __syncthreads();

#pragma unroll
        for (int ks = 0; ks < 128; ks += 32) {
            const int bof = (w2 * 16 + l15) * 136 + ks + quad * 8;
            const short8 b1 = *(const short8*)(B1 + bof);
            const short8 b2 = *(const short8*)(B2 + bof);
            const int aof = (mh * 16 + l15) * 136 + ks + quad * 8;
            const short8 a1 = *(const short8*)(A1 + aof);
            const short8 a2 = *(const short8*)(A2 + aof);
            acc = __builtin_amdgcn_mfma_f32_16x16x32_bf16(a1, b1, acc, 0, 0, 0);
            acc = __builtin_amdgcn_mfma_f32_16x16x32_bf16(a1, b2, acc, 0, 0, 0);
            acc = __builtin_amdgcn_mfma_f32_16x16x32_bf16(a2, b1, acc, 0, 0, 0);
        }
    }

    float* ct = tile;
#pragma unroll
    for (int r = 0; r < 4; r++)
        ct[(mh * 16 + quad * 4 + r) * 68 + w2 * 16 + l15] = acc[r];
    __syncthreads();

    const int b  = m0 >> 9;
    const int s0 = m0 & 511;
    if (isT) {
        const int n0g = nb * 64;
        const int mr = tid >> 4, nq = tid & 15;
        const float4 c  = *(const float4*)&ct[mr * 68 + nq * 4];
        const float4 bv = *(const float4*)&bh[n0g + nq * 4];
        // permuted store: mem (x,y,z,w) <- orig (0,2,1,3)
        float4 o;
        o.x = __builtin_amdgcn_exp2f((c.x + bv.x) * CC);
        o.y = __builtin_amdgcn_exp2f((c.z + bv.z) * CC);
        o.z = __builtin_amdgcn_exp2f((c.y + bv.y) * CC);
        o.w = __builtin_amdgcn_exp2f((c.w + bv.w) * CC);
        *(float4*)&Egt[(m0 + mr) * Hn + n0g + nq * 4] = o;
    } else {
        const int kq0 = (nb - 4) * 16;
        const int mr = tid & 31, nq = tid >> 5;
        const float4 c = *(const float4*)&ct[mr * 68 + nq * 4];
        // permuted store: mem (x,y,z,w) <- orig (0,2,1,3)
        float4 o;
        o.x = __builtin_amdgcn_exp2f(c.x * CC);
        o.y = __builtin_amdgcn_exp2f(c.z * CC);
        o.z = __builtin_amdgcn_exp2f(c.y * CC);
        o.w = __builtin_amdgcn_exp2f(c.w * CC);
        *(float4*)&Egp4[b * 131072 + (kq0 + nq) * 2048 + (s0 + mr) * 4] = o;
    }
}

// ---------------------------------------------------------------------------
// attn R23: 512-thread blocks, 4 rows, FULL k-range per thread.
// R22 was 1024-thr/kh-split: grid 512 at 2 blocks/CU = exactly 2 lockstep
// rounds, VALUBusy 60% (17us idle = tail + barrier windows with nothing to
// backfill). R20 failed by halving per-thread amortization (2 rows); this
// keeps 4-row amortization and doubles per-thread k-work instead:
//  - no kh split -> accl exchange (8KB + barrier) gone; barriers 6 -> 4
//  - LDS 40960 -> 24704 -> 4 blocks/CU (2048 thr/CU kept): 3 other blocks
//    backfill every barrier/tail window
//  - P1ROW body, eg/w4 s_load rotation, producers: byte-identical to R22
// Summation = single ascending-k pass (validated by R20: same absmax).
// ---------------------------------------------------------------------------
__global__ __launch_bounds__(512, 8) void attn_kernel(
    const float* __restrict__ hsrc, const float* __restrict__ Egt,
    const float* __restrict__ Egp4, const float* __restrict__ wa2,
    const float* __restrict__ cst,
    float* __restrict__ out, float* __restrict__ out_attn)
{
    // attn_l[4][512]@0 (8KB) ; red[32]@8192 ; part[4][4][64]f4@8320+pad
    __shared__ float  attn_l[4 * 512];
    __shared__ float  red[32];
    __shared__ float4 part[4 * 4 * 64];    // 16 KB, two-stage q reduction

    const int tid = threadIdx.x;           // 0..511
    const int b   = blockIdx.x & 3;
    const int t0  = (blockIdx.x >> 2) << 2;

    const float* __restrict__ egt = Egt + (b * Sn + t0) * Hn;   // block-uniform
    const float4* __restrict__ ep = (const float4*)(Egp4 + b * (Hn * Sn));

    float acc0 = 0.f, acc1 = 0.f, acc2 = 0.f, acc3 = 0.f;

    float4 w4c  = *(const float4*)&wa2[0];
    float4 eg0c = *(const float4*)&egt[0 * Hn];
    float4 eg1c = *(const float4*)&egt[1 * Hn];
    float4 eg2c = *(const float4*)&egt[2 * Hn];
    float4 eg3c = *(const float4*)&egt[3 * Hn];

    // Exact R22 body: eg/w4 fields referenced directly (SGPR operand inline).
#define P1ROW(EG, ACC)                                                        \
    {                                                                         \
        const float d0 = fmaf(cur.x, EG.x, 1.0f);                             \
        const float d1 = fmaf(cur.y, EG.y, 1.0f);                             \
        const float d2 = fmaf(cur.z, EG.z, 1.0f);                             \
        const float d3 = fmaf(cur.w, EG.w, 1.0f);                             \
        const float p0 = d0 * d2;                                             \
        const float p1 = d1 * d3;                                             \
        const float n0 = fmaf(w4c.x, d2, w4c.z * d0);                         \
        const float n1 = fmaf(w4c.y, d3, w4c.w * d1);                         \
        const float num = fmaf(n0, p1, n1 * p0);                              \
        ACC = fmaf(num, __builtin_amdgcn_rcpf(p0 * p1), ACC);                 \
    }

#pragma unroll 2
    for (int kk = 0; kk < 64; kk++) {
        const int k4n = (kk + 1) & 63;
        const float4 w4n  = *(const float4*)&wa2[k4n * 4];
        const float4 eg0n = *(const float4*)&egt[0 * Hn + k4n * 4];
        const float4 eg1n = *(const float4*)&egt[1 * Hn + k4n * 4];
        const float4 eg2n = *(const float4*)&egt[2 * Hn + k4n * 4];
        const float4 eg3n = *(const float4*)&egt[3 * Hn + k4n * 4];

        const float4 cur = ep[kk * Sn + tid];   // coalesced vector load

        P1ROW(eg0c, acc0)
        P1ROW(eg1c, acc1)
        P1ROW(eg2c, acc2)
        P1ROW(eg3c, acc3)

        w4c = w4n; eg0c = eg0n; eg1c = eg1n; eg2c = eg2n; eg3c = eg3n;
    }
#undef P1ROW

    const float accv[4] = {acc0, acc1, acc2, acc3};

    // ---- softmax: every thread owns full k of its 4 rows (no exchange) ----
    float ex[4];
    const float k0 = cst[0];
#pragma unroll
    for (int r = 0; r < 4; r++) {
        const float e1  = __builtin_amdgcn_exp2f(fmaf(-L2E, accv[r], k0));
        const float sig = __builtin_amdgcn_rcpf(1.0f + e1);
        ex[r] = __builtin_amdgcn_exp2f(L2E * sig);   // sig in (0,1)
    }
    const int lane = tid & 63, wid = tid >> 6;       // wid 0..7
#pragma unroll
    for (int r = 0; r < 4; r++) {
        float v = ex[r];
#pragma unroll
        for (int off = 32; off >= 1; off >>= 1) v += __shfl_xor(v, off, 64);
        if (lane == 0) red[r * 8 + wid] = v;
    }
    __syncthreads();

#pragma unroll
    for (int r = 0; r < 4; r++) {
        float tot = 0.f;
#pragma unroll
        for (int j = 0; j < 8; j++) tot += red[r * 8 + j];
        const float a = ex[r] * __builtin_amdgcn_rcpf(tot);
        attn_l[r * Sn + tid] = a;
        out_attn[(b * Sn + t0 + r) * Sn + tid] = a;
    }
    __syncthreads();

    // ---- phase 2: out rows = attn @ h. 8 q-groups of 64 t' each ----
    const int c4 = tid & 63;
    const int q  = tid >> 6;                 // 0..7, wave-uniform

    const float* __restrict__ hb = hsrc + (b * Sn + q * 64) * Hn + c4 * 4;

    float4 a4[4];
#pragma unroll
    for (int r = 0; r < 4; r++) a4[r] = (float4){0.f, 0.f, 0.f, 0.f};

#pragma unroll 2
    for (int j4 = 0; j4 < 16; j4++) {
        float4 wv[4];
#pragma unroll
        for (int r = 0; r < 4; r++)
            wv[r] = *(const float4*)&attn_l[r * Sn + q * 64 + j4 * 4];  // bcast
#pragma unroll
        for (int i = 0; i < 4; i++) {
            const float4 hv = *(const float4*)&hb[(j4 * 4 + i) * Hn];
#pragma unroll
            for (int r = 0; r < 4; r++) {
                const float wr = ((const float*)&wv[r])[i];
                a4[r].x = fmaf(wr, hv.x, a4[r].x);
                a4[r].y = fmaf(wr, hv.y, a4[r].y);
                a4[r].z = fmaf(wr, hv.z, a4[r].z);
                a4[r].w = fmaf(wr, hv.w, a4[r].w);
            }
        }
    }

    // two-stage q reduction into dedicated part (no aliasing)
    if (q < 4) {
#pragma unroll
        for (int r = 0; r < 4; r++) part[(q * 4 + r) * 64 + c4] = a4[r];
    }
    __syncthreads();
    if (q >= 4) {
#pragma unroll
        for (int r = 0; r < 4; r++) {
            float4 p = part[((q - 4) * 4 + r) * 64 + c4];
            p.x += a4[r].x; p.y += a4[r].y; p.z += a4[r].z; p.w += a4[r].w;
            part[((q - 4) * 4 + r) * 64 + c4] = p;
        }
    }
    __syncthreads();

    // final: 512 threads = 256 cols x 2 row-pairs; sum the 4 q-partials
    {
        const int col = tid & 255;
        const int rb  = (tid >> 8) * 2;      // 0 or 2
        const float* pf = (const float*)part;
#pragma unroll
        for (int i = 0; i < 2; i++) {
            const int r = rb + i;
            float s = 0.f;
#pragma unroll
            for (int qq = 0; qq < 4; qq++)
                s += pf[((qq * 4 + r) * 64 + (col >> 2)) * 4 + (col & 3)];
            out[(b * Sn + t0 + r) * Hn + col] = s;
        }
    }
}

extern "C" void kernel_launch(void* const* d_in, const int* in_sizes, int n_in,
                              void* d_out, int out_size, void* d_ws, size_t ws_size,
                              hipStream_t stream) {
    const float* h   = (const float*)d_in[0];
    const float* Wt  = (const float*)d_in[1];
    const float* Wtp = (const float*)d_in[2];
    const float* bh  = (const float*)d_in[3];
    const float* Wa  = (const float*)d_in[4];
    const float* ba  = (const float*)d_in[5];

    float* out      = (float*)d_out;                 // (B,S,H) = 524288
    float* out_attn = out + Bn * Sn * Hn;            // (B,S,S) = 1048576

    float* ws   = (float*)d_ws;
    float* Egt  = ws;                                 // 524288 f
    float* Egp4 = ws + 524288;                        // 524288 f
    float* wa2  = ws + 1048576;                       // 256 f
    float* cst  = ws + 1048832;                       // 1 f

    gemm_kernel<<<dim3(512), dim3(512), 0, stream>>>(
        h, Wt, Wtp, Wa, ba, bh, Egt, Egp4, wa2, cst);
    attn_kernel<<<dim3(Bn * (Sn / 4)), dim3(512), 0, stream>>>(
        h, Egt, Egp4, wa2, cst, out, out_attn);
}